// Round 1
// baseline (255.592 us; speedup 1.0000x reference)
//
#include <hip/hip_runtime.h>
#include <stdint.h>

#define ASG __attribute__((address_space(1)))
#define ASL __attribute__((address_space(3)))

typedef __bf16 bf16x8 __attribute__((ext_vector_type(8)));
typedef float f32x4 __attribute__((ext_vector_type(4)));

__device__ __forceinline__ unsigned short f2bf(float f) {
  unsigned int u = __builtin_bit_cast(unsigned int, f);
  u = (u + 0x7fffu + ((u >> 16) & 1u)) >> 16;
  return (unsigned short)u;
}

// ---------------- fp32 -> bf16 convert ----------------
__global__ __launch_bounds__(256) void k_f32_to_bf16(const float* __restrict__ in,
                                                     unsigned short* __restrict__ out,
                                                     int n4) {
  int i = blockIdx.x * 256 + threadIdx.x;
  if (i >= n4) return;
  float4 v = reinterpret_cast<const float4*>(in)[i];
  ushort4 o;
  o.x = f2bf(v.x); o.y = f2bf(v.y); o.z = f2bf(v.z); o.w = f2bf(v.w);
  reinterpret_cast<ushort4*>(out)[i] = o;
}

// ---------------- NT GEMM: C[m][n] = alpha * sum_k A[m][k]*B[n][k] (+bias[n]) ----------------
// 128x128 tile, 4 waves (2x2 of 64x64), BK=32, mfma_f32_16x16x32_bf16,
// global_load_lds width=16 staging (m97 structure).
template <int OUT_F32, int BIAS>
__global__ __launch_bounds__(256) void gemm_nt(
    const unsigned short* __restrict__ A, const unsigned short* __restrict__ B,
    void* __restrict__ Cv, const float* __restrict__ bias,
    int lda, int ldb, int ldc, int K, float alpha,
    long sA, long sB, long sC) {
  __shared__ __align__(16) char smem[16384];  // A tile 8KB | B tile 8KB
  const int tid = threadIdx.x;
  const int wid = tid >> 6, lane = tid & 63;
  const int bm0 = blockIdx.y * 128, bn0 = blockIdx.x * 128;
  A += (long)blockIdx.z * sA;
  B += (long)blockIdx.z * sB;

  // staging: 4 issues/thread of 16B; issue i covers combined bytes [i*4096 + wid*1024, +1024)
  const char* gsrc[4];
  char* ldst[4];
#pragma unroll
  for (int i = 0; i < 4; ++i) {
    int o = i * 4096 + wid * 1024;  // wave-uniform LDS byte offset
    ldst[i] = (char*)smem + o;
    int ob = o + (lane << 4);       // per-lane byte offset in combined buffer
    int e = (ob & 8191) >> 1;       // bf16 element within the 8KB tile
    int row = e >> 5, col = e & 31; // [128][32] row-major
    gsrc[i] = (const char*)((ob < 8192) ? (A + (long)(bm0 + row) * lda + col)
                                        : (B + (long)(bn0 + row) * ldb + col));
  }

  const int wr = wid >> 1, wc = wid & 1;
  int a_off[4], b_off[4];
#pragma unroll
  for (int f = 0; f < 4; ++f) {
    a_off[f] = ((wr * 64 + f * 16 + (lane & 15)) << 6) + ((lane >> 4) << 4);
    b_off[f] = 8192 + ((wc * 64 + f * 16 + (lane & 15)) << 6) + ((lane >> 4) << 4);
  }

  f32x4 acc[4][4] = {};

  for (int k0 = 0; k0 < K; k0 += 32) {
#pragma unroll
    for (int i = 0; i < 4; ++i)
      __builtin_amdgcn_global_load_lds((ASG void*)gsrc[i], (ASL void*)ldst[i], 16, 0, 0);
#pragma unroll
    for (int i = 0; i < 4; ++i) gsrc[i] += 64;  // advance 32 bf16 in k
    __syncthreads();  // compiler emits vmcnt(0) drain + barrier

    bf16x8 af[4], bfr[4];
#pragma unroll
    for (int f = 0; f < 4; ++f) {
      af[f]  = *reinterpret_cast<const bf16x8*>(smem + a_off[f]);
      bfr[f] = *reinterpret_cast<const bf16x8*>(smem + b_off[f]);
    }
#pragma unroll
    for (int fm = 0; fm < 4; ++fm)
#pragma unroll
      for (int fn = 0; fn < 4; ++fn)
        acc[fm][fn] = __builtin_amdgcn_mfma_f32_16x16x32_bf16(af[fm], bfr[fn], acc[fm][fn], 0, 0, 0);
    __syncthreads();
  }

  // epilogue: D col=lane&15, row=(lane>>4)*4+i  (m89-verified layout)
  const int r0 = bm0 + wr * 64 + ((lane >> 4) << 2);
  const int c0 = bn0 + wc * 64 + (lane & 15);
  if (OUT_F32) {
    float* C = (float*)Cv + (long)blockIdx.z * sC;
#pragma unroll
    for (int fm = 0; fm < 4; ++fm)
#pragma unroll
      for (int fn = 0; fn < 4; ++fn) {
        int col = c0 + fn * 16;
        float bb = BIAS ? bias[col] : 0.0f;
#pragma unroll
        for (int i = 0; i < 4; ++i)
          C[(long)(r0 + fm * 16 + i) * ldc + col] = acc[fm][fn][i] * alpha + bb;
      }
  } else {
    unsigned short* C = (unsigned short*)Cv + (long)blockIdx.z * sC;
#pragma unroll
    for (int fm = 0; fm < 4; ++fm)
#pragma unroll
      for (int fn = 0; fn < 4; ++fn) {
        int col = c0 + fn * 16;
        float bb = BIAS ? bias[col] : 0.0f;
#pragma unroll
        for (int i = 0; i < 4; ++i)
          C[(long)(r0 + fm * 16 + i) * ldc + col] = f2bf(acc[fm][fn][i] * alpha + bb);
      }
  }
}

// ---------------- row softmax: fp32 scores row (2048) -> bf16 P in-place ----------------
// P row r occupies the first 4096 bytes of scores row r (row stride 8192 B),
// i.e. as bf16 with lda = 4096 elements.
__global__ __launch_bounds__(256) void k_softmax_rows(float* __restrict__ scores) {
  long row = blockIdx.x;
  float* S = scores + row * 2048;
  const float4* S4 = reinterpret_cast<const float4*>(S);
  int t = threadIdx.x;
  int wid = t >> 6, lane = t & 63;
  float4 v0 = S4[t], v1 = S4[t + 256];

  float m = fmaxf(fmaxf(fmaxf(v0.x, v0.y), fmaxf(v0.z, v0.w)),
                  fmaxf(fmaxf(v1.x, v1.y), fmaxf(v1.z, v1.w)));
#pragma unroll
  for (int off = 32; off >= 1; off >>= 1) m = fmaxf(m, __shfl_xor(m, off));
  __shared__ float red[8];
  if (lane == 0) red[wid] = m;
  __syncthreads();
  m = fmaxf(fmaxf(red[0], red[1]), fmaxf(red[2], red[3]));

  float e[8];
  e[0] = __expf(v0.x - m); e[1] = __expf(v0.y - m);
  e[2] = __expf(v0.z - m); e[3] = __expf(v0.w - m);
  e[4] = __expf(v1.x - m); e[5] = __expf(v1.y - m);
  e[6] = __expf(v1.z - m); e[7] = __expf(v1.w - m);
  float s = e[0] + e[1] + e[2] + e[3] + e[4] + e[5] + e[6] + e[7];
#pragma unroll
  for (int off = 32; off >= 1; off >>= 1) s += __shfl_xor(s, off);
  if (lane == 0) red[4 + wid] = s;
  __syncthreads();  // also guarantees all reads of the row are done before writes
  s = red[4] + red[5] + red[6] + red[7];
  float inv = 1.0f / s;

  ushort4* P = reinterpret_cast<ushort4*>(S);
  ushort4 o0, o1;
  o0.x = f2bf(e[0] * inv); o0.y = f2bf(e[1] * inv);
  o0.z = f2bf(e[2] * inv); o0.w = f2bf(e[3] * inv);
  o1.x = f2bf(e[4] * inv); o1.y = f2bf(e[5] * inv);
  o1.z = f2bf(e[6] * inv); o1.w = f2bf(e[7] * inv);
  P[t] = o0;
  P[256 + t] = o1;
}

// ---------------- V [b][s][h] -> Vt [b][h][s] (bf16) ----------------
__global__ __launch_bounds__(256) void k_transpose_v(const unsigned short* __restrict__ V,
                                                     unsigned short* __restrict__ Vt) {
  __shared__ unsigned short tile[32][33];
  int b = blockIdx.z;
  int s0 = blockIdx.y * 32, h0 = blockIdx.x * 32;
  const unsigned short* Vb = V + (long)b * 2048 * 1024;
  unsigned short* Vtb = Vt + (long)b * 1024 * 2048;
  int tx = threadIdx.x & 31, ty = threadIdx.x >> 5;  // ty in [0,8)
#pragma unroll
  for (int i = 0; i < 4; ++i)
    tile[ty + 8 * i][tx] = Vb[(long)(s0 + ty + 8 * i) * 1024 + h0 + tx];
  __syncthreads();
#pragma unroll
  for (int i = 0; i < 4; ++i)
    Vtb[(long)(h0 + ty + 8 * i) * 2048 + s0 + tx] = tile[tx][ty + 8 * i];
}

extern "C" void kernel_launch(void* const* d_in, const int* in_sizes, int n_in,
                              void* d_out, int out_size, void* d_ws, size_t ws_size,
                              hipStream_t stream) {
  const float* X  = (const float*)d_in[0];
  const float* Wq = (const float*)d_in[1];
  const float* bq = (const float*)d_in[2];
  const float* Wk = (const float*)d_in[3];
  const float* bk = (const float*)d_in[4];
  const float* Wv = (const float*)d_in[5];
  const float* bv = (const float*)d_in[6];
  float* out = (float*)d_out;

  constexpr long Bb = 4, S = 2048, H = 1024;
  constexpr long MS = Bb * S;  // 8192 total tokens

  size_t off = 0;
  auto alloc = [&](size_t bytes) {
    char* p = (char*)d_ws + off;
    off += bytes;
    return p;
  };
  unsigned short* Xb  = (unsigned short*)alloc(MS * H * 2);   // 16.8 MB
  unsigned short* Wqb = (unsigned short*)alloc(H * H * 2);
  unsigned short* Wkb = (unsigned short*)alloc(H * H * 2);
  unsigned short* Wvb = (unsigned short*)alloc(H * H * 2);
  unsigned short* Qb  = (unsigned short*)alloc(MS * H * 2);
  unsigned short* Kb  = (unsigned short*)alloc(MS * H * 2);
  unsigned short* Vb  = (unsigned short*)alloc(MS * H * 2);
  unsigned short* Vt  = (unsigned short*)alloc(Bb * H * S * 2);
  float* scores = (float*)alloc(Bb * S * S * 4);              // 67 MB (P bf16 reuses it)
  (void)ws_size;

  // 1) convert inputs to bf16
  k_f32_to_bf16<<<dim3((int)(MS * H / 4 / 256)), 256, 0, stream>>>(X, Xb, (int)(MS * H / 4));
  k_f32_to_bf16<<<dim3((int)(H * H / 4 / 256)), 256, 0, stream>>>(Wq, Wqb, (int)(H * H / 4));
  k_f32_to_bf16<<<dim3((int)(H * H / 4 / 256)), 256, 0, stream>>>(Wk, Wkb, (int)(H * H / 4));
  k_f32_to_bf16<<<dim3((int)(H * H / 4 / 256)), 256, 0, stream>>>(Wv, Wvb, (int)(H * H / 4));

  // 2) Q/K/V = X @ W^T + b   (M=8192, N=1024, K=1024; bf16 out)
  gemm_nt<0, 1><<<dim3(8, 64, 1), 256, 0, stream>>>(Xb, Wqb, Qb, bq, 1024, 1024, 1024, 1024, 1.0f, 0, 0, 0);
  gemm_nt<0, 1><<<dim3(8, 64, 1), 256, 0, stream>>>(Xb, Wkb, Kb, bk, 1024, 1024, 1024, 1024, 1.0f, 0, 0, 0);
  gemm_nt<0, 1><<<dim3(8, 64, 1), 256, 0, stream>>>(Xb, Wvb, Vb, bv, 1024, 1024, 1024, 1024, 1.0f, 0, 0, 0);

  // 3) scores = Q @ K^T / sqrt(H)  (per batch: M=N=2048, K=1024; fp32 out)
  gemm_nt<1, 0><<<dim3(16, 16, 4), 256, 0, stream>>>(Qb, Kb, scores, nullptr, 1024, 1024, 2048, 1024,
                                                     0.03125f, S * H, S * H, S * S);

  // 4) softmax rows -> bf16 P in-place (P lda = 4096 bf16 elems)
  k_softmax_rows<<<dim3((int)MS), 256, 0, stream>>>(scores);

  // 5) V^T
  k_transpose_v<<<dim3(32, 64, 4), 256, 0, stream>>>(Vb, Vt);

  // 6) O = P @ V  (per batch: M=2048, N=1024, K=2048; fp32 out)
  gemm_nt<1, 0><<<dim3(8, 16, 4), 256, 0, stream>>>((const unsigned short*)scores, Vt, out, nullptr,
                                                    4096, 2048, 1024, 2048, 1.0f,
                                                    S * 4096L, H * S, S * H);
}

// Round 5
// 220.995 us; speedup vs baseline: 1.1566x; 1.1566x over previous
//
#include <hip/hip_runtime.h>
#include <stdint.h>

#define ASG __attribute__((address_space(1)))
#define ASL __attribute__((address_space(3)))

typedef __bf16 bf16x8 __attribute__((ext_vector_type(8)));
typedef float f32x4 __attribute__((ext_vector_type(4)));

__device__ __forceinline__ unsigned short f2bf(float f) {
  unsigned int u = __builtin_bit_cast(unsigned int, f);
  u = (u + 0x7fffu + ((u >> 16) & 1u)) >> 16;
  return (unsigned short)u;
}

// ---------------- fp32 -> bf16 convert ----------------
__global__ __launch_bounds__(256) void k_f32_to_bf16(const float* __restrict__ in,
                                                     unsigned short* __restrict__ out,
                                                     int n4) {
  int i = blockIdx.x * 256 + threadIdx.x;
  if (i >= n4) return;
  float4 v = reinterpret_cast<const float4*>(in)[i];
  ushort4 o;
  o.x = f2bf(v.x); o.y = f2bf(v.y); o.z = f2bf(v.z); o.w = f2bf(v.w);
  reinterpret_cast<ushort4*>(out)[i] = o;
}

// ---------------- fuse 3 biases into one [3072] ----------------
__global__ __launch_bounds__(256) void k_fuse_bias(const float* __restrict__ bq,
                                                   const float* __restrict__ bk,
                                                   const float* __restrict__ bv,
                                                   float* __restrict__ bf_) {
  int i = blockIdx.x * 256 + threadIdx.x;
  if (i >= 3072) return;
  bf_[i] = (i < 1024) ? bq[i] : (i < 2048 ? bk[i - 1024] : bv[i - 2048]);
}

// =====================================================================
// 256x256 tile, BK=64, 8 waves (2Mx4N), 8-phase pipelined NT GEMM.
// C[m][n] = alpha * sum_k A[m][k]*B[n][k] (+bias[n])
// LDS 128KB: buf d in {0,1}; A-half q at d*65536+q*16384 ([wr(2)][64][128B]),
// B-half q at d*65536+32768+q*16384 ([wc(4)][32][128B]).
// XOR swizzle: byte_in_row ^= ((row&7)<<4); applied on global SOURCE of
// global_load_lds (linear LDS dest) and on ds_read addresses.
// OUT_MODE: 0=bf16 store, 1=f32 store, 2=f32 accumulate (+=).
// =====================================================================
template <int OUT_MODE, int BIAS>
__global__ __launch_bounds__(512, 2) void gemm8(
    const unsigned short* __restrict__ A, const unsigned short* __restrict__ B,
    void* __restrict__ Cv, const float* __restrict__ bias,
    int lda, int ldb, int ldc, int K, float alpha,
    long sA, long sB, long sC) {
  __shared__ __align__(16) char smem[131072];
  const int tid = threadIdx.x;
  const int wid = tid >> 6, lane = tid & 63;
  const int wr = wid >> 2, wc = wid & 3;
  const int bm0 = blockIdx.y << 8, bn0 = blockIdx.x << 8;
  A += (long)blockIdx.z * sA;
  B += (long)blockIdx.z * sB;
  const int NT = K >> 6;  // 64-wide K tiles

  // ---- per-lane stage source offsets (elements), swizzle pre-applied ----
  const int csrc = ((lane & 7) ^ (lane >> 3)) << 3;  // element col within 64
  int offA[2][2], offB[2][2];
#pragma unroll
  for (int q = 0; q < 2; ++q)
#pragma unroll
    for (int l = 0; l < 2; ++l) {
      offA[q][l] = (bm0 + l * 128 + q * 64 + wid * 8 + (lane >> 3)) * lda + csrc;
      offB[q][l] = (bn0 + (l * 2 + wr) * 64 + q * 32 + wc * 8 + (lane >> 3)) * ldb + csrc;
    }

#define STG_A(Q, KT, D) do { int kk = (KT); if (kk >= NT) kk -= NT;            \
    __builtin_amdgcn_global_load_lds((ASG const void*)(A + offA[Q][0] + (kk << 6)), \
        (ASL void*)(smem + (D) * 65536 + (Q) * 16384 + wid * 1024), 16, 0, 0); \
    __builtin_amdgcn_global_load_lds((ASG const void*)(A + offA[Q][1] + (kk << 6)), \
        (ASL void*)(smem + (D) * 65536 + (Q) * 16384 + 8192 + wid * 1024), 16, 0, 0); } while (0)
#define STG_B(Q, KT, D) do { int kk = (KT); if (kk >= NT) kk -= NT;            \
    __builtin_amdgcn_global_load_lds((ASG const void*)(B + offB[Q][0] + (kk << 6)), \
        (ASL void*)(smem + (D) * 65536 + 32768 + (Q) * 16384 + wid * 1024), 16, 0, 0); \
    __builtin_amdgcn_global_load_lds((ASG const void*)(B + offB[Q][1] + (kk << 6)), \
        (ASL void*)(smem + (D) * 65536 + 32768 + (Q) * 16384 + 8192 + wid * 1024), 16, 0, 0); } while (0)

  // ---- ds_read addresses ----
  const int arow = (wr * 64 + (lane & 15)) << 7;
  const int brow = (wc * 32 + (lane & 15)) << 7;
  int colk[2];
#pragma unroll
  for (int ks = 0; ks < 2; ++ks)
    colk[ks] = ((ks << 6) + ((lane >> 4) << 4)) ^ ((lane & 7) << 4);

  bf16x8 afr[2][4][2];  // [q][mf][ks]
  bf16x8 bfr[2][2][2];  // [q][nf][ks]
  f32x4 acc[8][4] = {};

#define RDA(D, Q) do { _Pragma("unroll") for (int mf = 0; mf < 4; ++mf)        \
    _Pragma("unroll") for (int ks = 0; ks < 2; ++ks)                           \
      afr[Q][mf][ks] = *(const bf16x8*)(smem + (D) * 65536 + (Q) * 16384 +     \
                                        arow + (mf << 11) + colk[ks]); } while (0)
#define RDB(D, Q) do { _Pragma("unroll") for (int nf = 0; nf < 2; ++nf)        \
    _Pragma("unroll") for (int ks = 0; ks < 2; ++ks)                           \
      bfr[Q][nf][ks] = *(const bf16x8*)(smem + (D) * 65536 + 32768 + (Q) * 16384 + \
                                        brow + (nf << 11) + colk[ks]); } while (0)

#define MM(QM, QN) do { __builtin_amdgcn_s_setprio(1);                         \
    _Pragma("unroll") for (int mf = 0; mf < 4; ++mf)                           \
    _Pragma("unroll") for (int nf = 0; nf < 2; ++nf)                           \
    _Pragma("unroll") for (int ks = 0; ks < 2; ++ks)                           \
      acc[(QM) * 4 + mf][(QN) * 2 + nf] = __builtin_amdgcn_mfma_f32_16x16x32_bf16( \
          afr[QM][mf][ks], bfr[QN][nf][ks], acc[(QM) * 4 + mf][(QN) * 2 + nf], 0, 0, 0); \
    __builtin_amdgcn_s_setprio(0); } while (0)

  // phase: [reads (varargs)] [stage] | barrier; lgkmcnt(0); SB0 | MFMA | SB0 [vm] barrier
#define PH(STGS, MMS, VMS, ...) do {                                           \
    __VA_ARGS__;                                                               \
    STGS;                                                                      \
    __builtin_amdgcn_s_barrier();                                              \
    asm volatile("s_waitcnt lgkmcnt(0)" ::: "memory");                         \
    __builtin_amdgcn_sched_barrier(0);                                         \
    MMS;                                                                       \
    __builtin_amdgcn_sched_barrier(0);                                         \
    VMS;                                                                       \
    __builtin_amdgcn_s_barrier();                                              \
  } while (0)

  // ---- prologue: tile0 (all 4 halves) -> buf0, tile1 q0 halves -> buf1 ----
  STG_A(0, 0, 0); STG_B(0, 0, 0); STG_A(1, 0, 0); STG_B(1, 0, 0);
  STG_A(0, 1, 1); STG_B(0, 1, 1);
  asm volatile("s_waitcnt vmcnt(4)" ::: "memory");
  __builtin_amdgcn_s_barrier();

  const int NI = NT >> 1;
  for (int i = 0; i < NI; ++i) {
    const int t = 2 * i;
    // phases 1-4: compute tile t from buf0
    PH(STG_A(1, t + 1, 1), MM(0, 0), , RDA(0, 0); RDB(0, 0));
    PH(STG_B(1, t + 1, 1), MM(1, 0), , RDA(0, 1));
    PH(STG_B(0, t + 2, 0), MM(0, 1), , RDB(0, 1));
    PH(STG_A(0, t + 2, 0), MM(1, 1), asm volatile("s_waitcnt vmcnt(4)" ::: "memory"));
    // phases 5-8: compute tile t+1 from buf1
    PH(STG_A(1, t + 2, 0), MM(0, 0), , RDA(1, 0); RDB(1, 0));
    PH(STG_B(1, t + 2, 0), MM(1, 0), , RDA(1, 1));
    PH(STG_B(0, t + 3, 1), MM(0, 1), , RDB(1, 1));
    PH(STG_A(0, t + 3, 1), MM(1, 1), asm volatile("s_waitcnt vmcnt(4)" ::: "memory"));
  }

  // ---- epilogue: C write ----
#pragma unroll
  for (int qm = 0; qm < 2; ++qm)
#pragma unroll
    for (int mf = 0; mf < 4; ++mf)
#pragma unroll
      for (int qn = 0; qn < 2; ++qn)
#pragma unroll
        for (int nf = 0; nf < 2; ++nf) {
          const int row0 = bm0 + wr * 128 + qm * 64 + mf * 16 + ((lane >> 4) << 2);
          const int col = bn0 + wc * 64 + qn * 32 + nf * 16 + (lane & 15);
          f32x4 v = acc[qm * 4 + mf][qn * 2 + nf];
          const float bb = BIAS ? bias[col] : 0.0f;
          if (OUT_MODE == 0) {
            unsigned short* C = (unsigned short*)Cv + (long)blockIdx.z * sC;
#pragma unroll
            for (int j = 0; j < 4; ++j)
              C[(long)(row0 + j) * ldc + col] = f2bf(v[j] * alpha + bb);
          } else if (OUT_MODE == 1) {
            float* C = (float*)Cv + (long)blockIdx.z * sC;
#pragma unroll
            for (int j = 0; j < 4; ++j)
              C[(long)(row0 + j) * ldc + col] = v[j] * alpha + bb;
          } else {
            float* C = (float*)Cv + (long)blockIdx.z * sC;
#pragma unroll
            for (int j = 0; j < 4; ++j)
              C[(long)(row0 + j) * ldc + col] += v[j] * alpha;
          }
        }
#undef STG_A
#undef STG_B
#undef RDA
#undef RDB
#undef MM
#undef PH
}

// ---------------- row softmax on bf16 scores, in place ----------------
__global__ __launch_bounds__(256) void k_softmax_bf16(unsigned short* __restrict__ S) {
  long row = blockIdx.x;
  unsigned short* R = S + row * 2048;
  int t = threadIdx.x;
  int wid = t >> 6, lane = t & 63;
  uint4 raw = reinterpret_cast<const uint4*>(R)[t];
  unsigned int w[4] = {raw.x, raw.y, raw.z, raw.w};
  float v[8];
#pragma unroll
  for (int j = 0; j < 4; ++j) {
    v[2 * j]     = __builtin_bit_cast(float, (unsigned int)(w[j] << 16));
    v[2 * j + 1] = __builtin_bit_cast(float, (unsigned int)(w[j] & 0xffff0000u));
  }
  float m = v[0];
#pragma unroll
  for (int j = 1; j < 8; ++j) m = fmaxf(m, v[j]);
#pragma unroll
  for (int off = 32; off >= 1; off >>= 1) m = fmaxf(m, __shfl_xor(m, off));
  __shared__ float red[8];
  if (lane == 0) red[wid] = m;
  __syncthreads();
  m = fmaxf(fmaxf(red[0], red[1]), fmaxf(red[2], red[3]));

  float e[8], s = 0.f;
#pragma unroll
  for (int j = 0; j < 8; ++j) { e[j] = __expf(v[j] - m); s += e[j]; }
#pragma unroll
  for (int off = 32; off >= 1; off >>= 1) s += __shfl_xor(s, off);
  if (lane == 0) red[4 + wid] = s;
  __syncthreads();
  s = red[4] + red[5] + red[6] + red[7];
  float inv = 1.0f / s;

  uint4 o;
  unsigned int* ow = &o.x;
#pragma unroll
  for (int j = 0; j < 4; ++j)
    ow[j] = (unsigned int)f2bf(e[2 * j] * inv) |
            ((unsigned int)f2bf(e[2 * j + 1] * inv) << 16);
  reinterpret_cast<uint4*>(R)[t] = o;
}

// ---------------- V [b][s][h] (stride 3072) -> Vt [b][h][s] ----------------
__global__ __launch_bounds__(256) void k_transpose_v(const unsigned short* __restrict__ V,
                                                     unsigned short* __restrict__ Vt) {
  __shared__ unsigned short tile[32][33];
  int b = blockIdx.z;
  int s0 = blockIdx.y * 32, h0 = blockIdx.x * 32;
  const unsigned short* Vb = V + (long)b * 2048 * 3072;
  unsigned short* Vtb = Vt + (long)b * 1024 * 2048;
  int tx = threadIdx.x & 31, ty = threadIdx.x >> 5;
#pragma unroll
  for (int i = 0; i < 4; ++i)
    tile[ty + 8 * i][tx] = Vb[(long)(s0 + ty + 8 * i) * 3072 + h0 + tx];
  __syncthreads();
#pragma unroll
  for (int i = 0; i < 4; ++i)
    Vtb[(long)(h0 + ty + 8 * i) * 2048 + s0 + tx] = tile[tx][ty + 8 * i];
}

extern "C" void kernel_launch(void* const* d_in, const int* in_sizes, int n_in,
                              void* d_out, int out_size, void* d_ws, size_t ws_size,
                              hipStream_t stream) {
  const float* X  = (const float*)d_in[0];
  const float* Wq = (const float*)d_in[1];
  const float* bq = (const float*)d_in[2];
  const float* Wk = (const float*)d_in[3];
  const float* bk = (const float*)d_in[4];
  const float* Wv = (const float*)d_in[5];
  const float* bv = (const float*)d_in[6];
  float* out = (float*)d_out;
  (void)in_sizes; (void)n_in; (void)out_size; (void)ws_size;

  constexpr long S = 2048, H = 1024;
  constexpr long MS = 4 * S;  // 8192 tokens

  size_t off = 0;
  auto alloc = [&](size_t bytes) { char* p = (char*)d_ws + off; off += bytes; return p; };
  unsigned short* Xb    = (unsigned short*)alloc(MS * H * 2);        // 16.8 MB
  unsigned short* Wb    = (unsigned short*)alloc(3 * H * H * 2);     // 6.3 MB (Wq|Wk|Wv)
  float*          biasF = (float*)alloc(3 * H * 4);                  // 12 KB
  unsigned short* QKVb  = (unsigned short*)alloc(MS * 3 * H * 2);    // 50.3 MB
  unsigned short* Vt    = (unsigned short*)alloc(4 * H * S * 2);     // 16.8 MB
  unsigned short* Sb    = (unsigned short*)alloc(4 * S * S * 2);     // 33.6 MB

  // 1) converts + bias fuse
  k_f32_to_bf16<<<dim3(8192), 256, 0, stream>>>(X, Xb, (int)(MS * H / 4));
  k_f32_to_bf16<<<dim3(1024), 256, 0, stream>>>(Wq, Wb, (int)(H * H / 4));
  k_f32_to_bf16<<<dim3(1024), 256, 0, stream>>>(Wk, Wb + H * H, (int)(H * H / 4));
  k_f32_to_bf16<<<dim3(1024), 256, 0, stream>>>(Wv, Wb + 2 * H * H, (int)(H * H / 4));
  k_fuse_bias<<<dim3(12), 256, 0, stream>>>(bq, bk, bv, biasF);

  // 2) fused QKV = X @ [Wq|Wk|Wv]^T + b  (M=8192, N=3072, K=1024; bf16 out)
  gemm8<0, 1><<<dim3(12, 32, 1), 512, 0, stream>>>(Xb, Wb, QKVb, biasF,
                                                   1024, 1024, 3072, 1024, 1.0f, 0, 0, 0);

  // 3) scores = Q @ K^T / 32  (per batch M=N=2048, K=1024; bf16 out)
  gemm8<0, 0><<<dim3(8, 8, 4), 512, 0, stream>>>(QKVb, QKVb + 1024, Sb, nullptr,
                                                 3072, 3072, 2048, 1024, 0.03125f,
                                                 S * 3 * H, S * 3 * H, S * S);

  // 4) softmax rows in place (bf16)
  k_softmax_bf16<<<dim3((int)MS), 256, 0, stream>>>(Sb);

  // 5) V^T (from fused QKV, col offset 2048)
  k_transpose_v<<<dim3(32, 64, 4), 256, 0, stream>>>(QKVb + 2048, Vt);

  // 6) O = P @ V, split-K (2 x K=1024): write then accumulate
  gemm8<1, 0><<<dim3(4, 8, 4), 512, 0, stream>>>(Sb, Vt, out, nullptr,
                                                 2048, 2048, 1024, 1024, 1.0f,
                                                 S * S, H * S, S * H);
  gemm8<2, 0><<<dim3(4, 8, 4), 512, 0, stream>>>(Sb + 1024, Vt + 1024, out, nullptr,
                                                 2048, 2048, 1024, 1024, 1.0f,
                                                 S * S, H * S, S * H);
}

// Round 7
// 175.616 us; speedup vs baseline: 1.4554x; 1.2584x over previous
//
#include <hip/hip_runtime.h>
#include <stdint.h>

#define ASG __attribute__((address_space(1)))
#define ASL __attribute__((address_space(3)))

typedef __bf16 bf16x8 __attribute__((ext_vector_type(8)));
typedef float f32x4 __attribute__((ext_vector_type(4)));

__device__ __forceinline__ unsigned short f2bf(float f) {
  unsigned int u = __builtin_bit_cast(unsigned int, f);
  u = (u + 0x7fffu + ((u >> 16) & 1u)) >> 16;
  return (unsigned short)u;
}

// ---------------- fused prep: converts X,Wq,Wk,Wv to bf16 + bias concat ----------------
// grid: [0,8192) X float4s; [8192,9216) Wq; [9216,10240) Wk; [10240,11264) Wv;
// [11264,11276) bias copy.
__global__ __launch_bounds__(256) void k_prep(
    const float* __restrict__ X, const float* __restrict__ Wq,
    const float* __restrict__ Wk, const float* __restrict__ Wv,
    const float* __restrict__ bq, const float* __restrict__ bk,
    const float* __restrict__ bv,
    unsigned short* __restrict__ Xb, float* __restrict__ biasF) {
  const int bid = blockIdx.x, tid = threadIdx.x;
  unsigned short* Wb = Xb + 8388608;  // 8192*1024 elements
  if (bid < 11264) {
    const float* src;
    ushort4* dst;
    int j;
    if (bid < 8192) {
      j = bid * 256 + tid; src = X; dst = (ushort4*)Xb;
    } else {
      int w = (bid - 8192) >> 10;              // 0,1,2
      j = ((bid - 8192) & 1023) * 256 + tid;   // < 262144
      src = (w == 0) ? Wq : (w == 1 ? Wk : Wv);
      dst = (ushort4*)(Wb + (long)w * 1048576);
    }
    float4 v = reinterpret_cast<const float4*>(src)[j];
    ushort4 o;
    o.x = f2bf(v.x); o.y = f2bf(v.y); o.z = f2bf(v.z); o.w = f2bf(v.w);
    dst[j] = o;
  } else {
    int i = (bid - 11264) * 256 + tid;
    if (i < 3072)
      biasF[i] = (i < 1024) ? bq[i] : (i < 2048 ? bk[i - 1024] : bv[i - 2048]);
  }
}

// =====================================================================
// 128x256 tile, BK=64, 8 waves (2Mx4N, wave-tile 64x64), 3-buffer LDS ring,
// 2 phases per K-tile, vmcnt(6) 2-tiles-ahead prefetch. NT GEMM:
// C[m][n] = alpha * sum_k A[m][k]*B[n][k] (+bias[n])
// LDS 3 x 48KB: buf b at b*49152: A [128][64] bf16 (16KB), B [256][64] (32KB).
// XOR swizzle: 16B-block-in-row ^= (row&7); applied on global SOURCE of
// global_load_lds (linear LDS dest) and on ds_read addresses.
// OUT_MODE: 0=bf16 store, 1=f32 store.
// =====================================================================
template <int OUT_MODE, int BIAS>
__global__ __launch_bounds__(512, 2) void gemm3r(
    const unsigned short* __restrict__ A, const unsigned short* __restrict__ B,
    void* __restrict__ Cv, const float* __restrict__ bias,
    int lda, int ldb, int ldc, int K, float alpha,
    long sA, long sB, long sC) {
  __shared__ __align__(16) char smem[147456];
  const int tid = threadIdx.x;
  const int wid = tid >> 6, lane = tid & 63;
  const int wr = wid >> 2, wc = wid & 3;
  const int bm0 = blockIdx.y << 7, bn0 = blockIdx.x << 8;
  A += (long)blockIdx.z * sA;
  B += (long)blockIdx.z * sB;
  const int NT = K >> 6;  // number of 64-wide K tiles

  // ---- staging source addresses (per-lane), swizzle pre-applied ----
  const int srow = tid >> 3;                       // 0..63 within a unit
  const int scol = (((tid & 7) ^ (srow & 7)) << 3);  // element col within 64
  long gA[2], gB[4];
#pragma unroll
  for (int u = 0; u < 2; ++u)
    gA[u] = (long)(bm0 + u * 64 + srow) * lda + scol;
#pragma unroll
  for (int u = 0; u < 4; ++u)
    gB[u] = (long)(bn0 + u * 64 + srow) * ldb + scol;

  // one STG = 512 threads x 16B = 8KB = 64 rows of 128B
#define STG(PTR, GOFF, KK, LDSOFF)                                             \
  __builtin_amdgcn_global_load_lds((ASG const void*)((PTR) + (GOFF) + ((KK) << 6)), \
      (ASL void*)(smem + (LDSOFF) + wid * 1024), 16, 0, 0)

#define STG_P1(KK, SB_) do { int kk = (KK); if (kk >= NT) kk -= NT;            \
    STG(A, gA[0], kk, (SB_));                                                  \
    STG(A, gA[1], kk, (SB_) + 8192);                                           \
    STG(B, gB[0], kk, (SB_) + 16384); } while (0)
#define STG_P2(KK, SB_) do { int kk = (KK); if (kk >= NT) kk -= NT;            \
    STG(B, gB[1], kk, (SB_) + 24576);                                          \
    STG(B, gB[2], kk, (SB_) + 32768);                                          \
    STG(B, gB[3], kk, (SB_) + 40960); } while (0)

  // ---- ds_read addresses ----
  const int arow0 = (wr * 64 + (lane & 15)) << 7;          // byte, + mf*2048
  const int brow0 = 16384 + ((wc * 64 + (lane & 15)) << 7); // byte, + nf*2048
  int colk[2];
#pragma unroll
  for (int ks = 0; ks < 2; ++ks)
    colk[ks] = (((ks << 2) + (lane >> 4)) ^ (lane & 7)) << 4;

  bf16x8 afr[4][2];    // [mf][ks]
  bf16x8 b01[2][2];    // [nf 0-1][ks]
  bf16x8 b23[2][2];    // [nf 2-3][ks]
  f32x4 acc[4][4] = {};

#define RDA(CB) do { _Pragma("unroll") for (int mf = 0; mf < 4; ++mf)          \
    _Pragma("unroll") for (int ks = 0; ks < 2; ++ks)                           \
      afr[mf][ks] = *(const bf16x8*)(smem + (CB) + arow0 + (mf << 11) + colk[ks]); } while (0)
#define RDB01(CB) do { _Pragma("unroll") for (int nf = 0; nf < 2; ++nf)        \
    _Pragma("unroll") for (int ks = 0; ks < 2; ++ks)                           \
      b01[nf][ks] = *(const bf16x8*)(smem + (CB) + brow0 + (nf << 11) + colk[ks]); } while (0)
#define RDB23(CB) do { _Pragma("unroll") for (int nf = 0; nf < 2; ++nf)        \
    _Pragma("unroll") for (int ks = 0; ks < 2; ++ks)                           \
      b23[nf][ks] = *(const bf16x8*)(smem + (CB) + brow0 + ((nf + 2) << 11) + colk[ks]); } while (0)

#define MM(BF, NB) do { __builtin_amdgcn_s_setprio(1);                         \
    _Pragma("unroll") for (int mf = 0; mf < 4; ++mf)                           \
    _Pragma("unroll") for (int nf = 0; nf < 2; ++nf)                           \
    _Pragma("unroll") for (int ks = 0; ks < 2; ++ks)                           \
      acc[mf][(NB) + nf] = __builtin_amdgcn_mfma_f32_16x16x32_bf16(            \
          afr[mf][ks], BF[nf][ks], acc[mf][(NB) + nf], 0, 0, 0);               \
    __builtin_amdgcn_s_setprio(0); } while (0)

  // ---- prologue: tile0 -> buf0, tile1 -> buf1 (12 issues), drain to 6 ----
  STG_P1(0, 0); STG_P2(0, 0);
  STG_P1(1, 49152); STG_P2(1, 49152);
  asm volatile("s_waitcnt vmcnt(6)" ::: "memory");
  __builtin_amdgcn_s_barrier();

  int bc = 0, bs = 2 * 49152;  // compute-buffer offset, stage-buffer offset
  for (int t = 0; t < NT; ++t) {
    // phase 1: read A + B01 of tile t; stage first half of tile t+2
    RDA(bc); RDB01(bc);
    STG_P1(t + 2, bs);
    __builtin_amdgcn_s_barrier();
    asm volatile("s_waitcnt lgkmcnt(0)" ::: "memory");
    __builtin_amdgcn_sched_barrier(0);
    MM(b01, 0);
    __builtin_amdgcn_sched_barrier(0);
    __builtin_amdgcn_s_barrier();
    // phase 2: read B23; stage second half of tile t+2; ensure t+1 landed
    RDB23(bc);
    STG_P2(t + 2, bs);
    __builtin_amdgcn_s_barrier();
    asm volatile("s_waitcnt lgkmcnt(0)" ::: "memory");
    __builtin_amdgcn_sched_barrier(0);
    MM(b23, 2);
    __builtin_amdgcn_sched_barrier(0);
    asm volatile("s_waitcnt vmcnt(6)" ::: "memory");
    __builtin_amdgcn_s_barrier();
    bc += 49152; if (bc == 147456) bc = 0;
    bs += 49152; if (bs == 147456) bs = 0;
  }

  // ---- epilogue: C write (D: col=lane&15, row=(lane>>4)*4+j) ----
  const int r0 = bm0 + wr * 64 + ((lane >> 4) << 2);
  const int c0 = bn0 + wc * 64 + (lane & 15);
#pragma unroll
  for (int mf = 0; mf < 4; ++mf)
#pragma unroll
    for (int nf = 0; nf < 4; ++nf) {
      const int row0 = r0 + mf * 16;
      const int col = c0 + nf * 16;
      f32x4 v = acc[mf][nf];
      const float bb = BIAS ? bias[col] : 0.0f;
      if (OUT_MODE == 0) {
        unsigned short* C = (unsigned short*)Cv + (long)blockIdx.z * sC;
#pragma unroll
        for (int j = 0; j < 4; ++j)
          C[(long)(row0 + j) * ldc + col] = f2bf(v[j] * alpha + bb);
      } else {
        float* C = (float*)Cv + (long)blockIdx.z * sC;
#pragma unroll
        for (int j = 0; j < 4; ++j)
          C[(long)(row0 + j) * ldc + col] = v[j] * alpha + bb;
      }
    }
#undef STG
#undef STG_P1
#undef STG_P2
#undef RDA
#undef RDB01
#undef RDB23
#undef MM
}

// ---------------- row softmax on bf16 scores, in place ----------------
__global__ __launch_bounds__(256) void k_softmax_bf16(unsigned short* __restrict__ S) {
  long row = blockIdx.x;
  unsigned short* R = S + row * 2048;
  int t = threadIdx.x;
  int wid = t >> 6, lane = t & 63;
  uint4 raw = reinterpret_cast<const uint4*>(R)[t];
  unsigned int w[4] = {raw.x, raw.y, raw.z, raw.w};
  float v[8];
#pragma unroll
  for (int j = 0; j < 4; ++j) {
    v[2 * j]     = __builtin_bit_cast(float, (unsigned int)(w[j] << 16));
    v[2 * j + 1] = __builtin_bit_cast(float, (unsigned int)(w[j] & 0xffff0000u));
  }
  float m = v[0];
#pragma unroll
  for (int j = 1; j < 8; ++j) m = fmaxf(m, v[j]);
#pragma unroll
  for (int off = 32; off >= 1; off >>= 1) m = fmaxf(m, __shfl_xor(m, off));
  __shared__ float red[8];
  if (lane == 0) red[wid] = m;
  __syncthreads();
  m = fmaxf(fmaxf(red[0], red[1]), fmaxf(red[2], red[3]));

  float e[8], s = 0.f;
#pragma unroll
  for (int j = 0; j < 8; ++j) { e[j] = __expf(v[j] - m); s += e[j]; }
#pragma unroll
  for (int off = 32; off >= 1; off >>= 1) s += __shfl_xor(s, off);
  if (lane == 0) red[4 + wid] = s;
  __syncthreads();
  s = red[4] + red[5] + red[6] + red[7];
  float inv = 1.0f / s;

  uint4 o;
  unsigned int* ow = &o.x;
#pragma unroll
  for (int j = 0; j < 4; ++j)
    ow[j] = (unsigned int)f2bf(e[2 * j] * inv) |
            ((unsigned int)f2bf(e[2 * j + 1] * inv) << 16);
  reinterpret_cast<uint4*>(R)[t] = o;
}

// ---------------- V [b][s][h] (stride 3072) -> Vt [b][h][s] ----------------
__global__ __launch_bounds__(256) void k_transpose_v(const unsigned short* __restrict__ V,
                                                     unsigned short* __restrict__ Vt) {
  __shared__ unsigned short tile[32][33];
  int b = blockIdx.z;
  int s0 = blockIdx.y * 32, h0 = blockIdx.x * 32;
  const unsigned short* Vb = V + (long)b * 2048 * 3072;
  unsigned short* Vtb = Vt + (long)b * 1024 * 2048;
  int tx = threadIdx.x & 31, ty = threadIdx.x >> 5;
#pragma unroll
  for (int i = 0; i < 4; ++i)
    tile[ty + 8 * i][tx] = Vb[(long)(s0 + ty + 8 * i) * 3072 + h0 + tx];
  __syncthreads();
#pragma unroll
  for (int i = 0; i < 4; ++i)
    Vtb[(long)(h0 + ty + 8 * i) * 2048 + s0 + tx] = tile[tx][ty + 8 * i];
}

extern "C" void kernel_launch(void* const* d_in, const int* in_sizes, int n_in,
                              void* d_out, int out_size, void* d_ws, size_t ws_size,
                              hipStream_t stream) {
  const float* X  = (const float*)d_in[0];
  const float* Wq = (const float*)d_in[1];
  const float* bq = (const float*)d_in[2];
  const float* Wk = (const float*)d_in[3];
  const float* bk = (const float*)d_in[4];
  const float* Wv = (const float*)d_in[5];
  const float* bv = (const float*)d_in[6];
  float* out = (float*)d_out;
  (void)in_sizes; (void)n_in; (void)out_size; (void)ws_size;

  constexpr long S = 2048, H = 1024;
  constexpr long MS = 4 * S;  // 8192 tokens

  size_t off = 0;
  auto alloc = [&](size_t bytes) { char* p = (char*)d_ws + off; off += bytes; return p; };
  unsigned short* Xb    = (unsigned short*)alloc(MS * H * 2);        // 16.8 MB
  unsigned short* Wb    = (unsigned short*)alloc(3 * H * H * 2);     // 6.3 MB (contiguous after Xb)
  float*          biasF = (float*)alloc(3 * H * 4);                  // 12 KB
  unsigned short* QKVb  = (unsigned short*)alloc(MS * 3 * H * 2);    // 50.3 MB
  unsigned short* Vt    = (unsigned short*)alloc(4 * H * S * 2);     // 16.8 MB
  unsigned short* Sb    = (unsigned short*)alloc(4 * S * S * 2);     // 33.6 MB
  (void)Wb;

  // 1) fused converts + bias
  k_prep<<<dim3(11276), 256, 0, stream>>>(X, Wq, Wk, Wv, bq, bk, bv, Xb, biasF);

  // 2) fused QKV = X @ [Wq|Wk|Wv]^T + b  (M=8192, N=3072, K=1024; bf16 out) — 768 blocks = 3.0 rounds
  gemm3r<0, 1><<<dim3(12, 64, 1), 512, 0, stream>>>(Xb, Xb + MS * H, QKVb, biasF,
                                                    1024, 1024, 3072, 1024, 1.0f, 0, 0, 0);

  // 3) scores = Q @ K^T / 32  (per batch M=2048, N=2048, K=1024; bf16 out) — 512 blocks = 2.0 rounds
  gemm3r<0, 0><<<dim3(8, 16, 4), 512, 0, stream>>>(QKVb, QKVb + 1024, Sb, nullptr,
                                                   3072, 3072, 2048, 1024, 0.03125f,
                                                   S * 3 * H, S * 3 * H, S * S);

  // 4) softmax rows in place (bf16)
  k_softmax_bf16<<<dim3((int)MS), 256, 0, stream>>>(Sb);

  // 5) V^T (from fused QKV, col offset 2048)
  k_transpose_v<<<dim3(32, 64, 4), 256, 0, stream>>>(QKVb + 2048, Vt);

  // 6) O = P @ V  (per batch M=2048, N=1024, K=2048; f32 out) — 256 blocks = 1.0 round
  gemm3r<1, 0><<<dim3(4, 16, 4), 512, 0, stream>>>(Sb, Vt, out, nullptr,
                                                   2048, 2048, 1024, 2048, 1.0f,
                                                   S * S, H * S, S * H);
}

// Round 8
// 169.990 us; speedup vs baseline: 1.5036x; 1.0331x over previous
//
#include <hip/hip_runtime.h>
#include <stdint.h>

#define ASG __attribute__((address_space(1)))
#define ASL __attribute__((address_space(3)))

typedef __bf16 bf16x8 __attribute__((ext_vector_type(8)));
typedef float f32x4 __attribute__((ext_vector_type(4)));

__device__ __forceinline__ unsigned short f2bf(float f) {
  unsigned int u = __builtin_bit_cast(unsigned int, f);
  u = (u + 0x7fffu + ((u >> 16) & 1u)) >> 16;
  return (unsigned short)u;
}

// ---------------- fused prep: converts X,Wq,Wk,Wv to bf16 + bias concat ----------------
__global__ __launch_bounds__(256) void k_prep(
    const float* __restrict__ X, const float* __restrict__ Wq,
    const float* __restrict__ Wk, const float* __restrict__ Wv,
    const float* __restrict__ bq, const float* __restrict__ bk,
    const float* __restrict__ bv,
    unsigned short* __restrict__ Xb, float* __restrict__ biasF) {
  const int bid = blockIdx.x, tid = threadIdx.x;
  unsigned short* Wb = Xb + 8388608;  // 8192*1024 elements
  if (bid < 11264) {
    const float* src;
    ushort4* dst;
    int j;
    if (bid < 8192) {
      j = bid * 256 + tid; src = X; dst = (ushort4*)Xb;
    } else {
      int w = (bid - 8192) >> 10;              // 0,1,2
      j = ((bid - 8192) & 1023) * 256 + tid;   // < 262144
      src = (w == 0) ? Wq : (w == 1 ? Wk : Wv);
      dst = (ushort4*)(Wb + (long)w * 1048576);
    }
    float4 v = reinterpret_cast<const float4*>(src)[j];
    ushort4 o;
    o.x = f2bf(v.x); o.y = f2bf(v.y); o.z = f2bf(v.z); o.w = f2bf(v.w);
    dst[j] = o;
  } else {
    int i = (bid - 11264) * 256 + tid;
    if (i < 3072)
      biasF[i] = (i < 1024) ? bq[i] : (i < 2048 ? bk[i - 1024] : bv[i - 2048]);
  }
}

// =====================================================================
// 128x256 tile, BK=64, 8 waves (2Mx4N, wave-tile 64x64), 3-buffer LDS ring,
// ONE barrier per K-tile, compiler-interleaved counted lgkmcnt between
// ds_read and MFMA (no drain before MFMA), next-tile A+B01 reads prefetched
// right after the barrier. vmcnt(6) = 2-tiles-ahead staging. NT GEMM:
// C[m][n] = alpha * sum_k A[m][k]*B[n][k] (+bias[n])
// LDS 3 x 48KB: buf b at b*49152: A [128][64] bf16 (16KB), B [256][64] (32KB).
// XOR swizzle: 16B-block-in-row ^= (row&7); on global SOURCE of
// global_load_lds (linear LDS dest) and on ds_read addresses.
// Safety: s_waitcnt vmcnt(6) lgkmcnt(0) before the per-iter barrier ensures
// (a) all this wave's reads of tile t are complete (free — already consumed),
// (b) tile t+1 landed; barrier extends both guarantees across waves. STG at
// iter t targets (t+2)%3, whose last reads were iter t-1 (pre-barrier). 
// OUT_MODE: 0=bf16 store, 1=f32 store.
// =====================================================================
template <int OUT_MODE, int BIAS>
__global__ __launch_bounds__(512, 2) void gemm3p(
    const unsigned short* __restrict__ A, const unsigned short* __restrict__ B,
    void* __restrict__ Cv, const float* __restrict__ bias,
    int lda, int ldb, int ldc, int K, float alpha,
    long sA, long sB, long sC) {
  __shared__ __align__(16) char smem[147456];
  const int tid = threadIdx.x;
  const int wid = tid >> 6, lane = tid & 63;
  const int wr = wid >> 2, wc = wid & 3;
  const int bm0 = blockIdx.y << 7, bn0 = blockIdx.x << 8;
  A += (long)blockIdx.z * sA;
  B += (long)blockIdx.z * sB;
  const int NT = K >> 6;  // number of 64-wide K tiles

  // ---- staging source addresses (per-lane), swizzle pre-applied ----
  const int srow = tid >> 3;                         // 0..63 within a unit
  const int scol = (((tid & 7) ^ (srow & 7)) << 3);  // element col within 64
  long gA[2], gB[4];
#pragma unroll
  for (int u = 0; u < 2; ++u)
    gA[u] = (long)(bm0 + u * 64 + srow) * lda + scol;
#pragma unroll
  for (int u = 0; u < 4; ++u)
    gB[u] = (long)(bn0 + u * 64 + srow) * ldb + scol;

#define STG(PTR, GOFF, KK, LDSOFF)                                             \
  __builtin_amdgcn_global_load_lds((ASG const void*)((PTR) + (GOFF) + ((KK) << 6)), \
      (ASL void*)(smem + (LDSOFF) + wid * 1024), 16, 0, 0)

#define STG_ALL(KK, SB_) do { int kk = (KK); if (kk >= NT) kk -= NT;           \
    STG(A, gA[0], kk, (SB_));                                                  \
    STG(A, gA[1], kk, (SB_) + 8192);                                           \
    STG(B, gB[0], kk, (SB_) + 16384);                                          \
    STG(B, gB[1], kk, (SB_) + 24576);                                          \
    STG(B, gB[2], kk, (SB_) + 32768);                                          \
    STG(B, gB[3], kk, (SB_) + 40960); } while (0)

  // ---- ds_read addresses ----
  const int arow0 = (wr * 64 + (lane & 15)) << 7;           // byte, + mf*2048
  const int brow0 = 16384 + ((wc * 64 + (lane & 15)) << 7); // byte, + nf*2048
  int colk[2];
#pragma unroll
  for (int ks = 0; ks < 2; ++ks)
    colk[ks] = (((ks << 2) + (lane >> 4)) ^ (lane & 7)) << 4;

  bf16x8 afr[4][2];    // [mf][ks]
  bf16x8 b01[2][2];    // [nf 0-1][ks]
  bf16x8 b23[2][2];    // [nf 2-3][ks]
  f32x4 acc[4][4] = {};

#define RDA(CB) do { _Pragma("unroll") for (int mf = 0; mf < 4; ++mf)          \
    _Pragma("unroll") for (int ks = 0; ks < 2; ++ks)                           \
      afr[mf][ks] = *(const bf16x8*)(smem + (CB) + arow0 + (mf << 11) + colk[ks]); } while (0)
#define RDB01(CB) do { _Pragma("unroll") for (int nf = 0; nf < 2; ++nf)        \
    _Pragma("unroll") for (int ks = 0; ks < 2; ++ks)                           \
      b01[nf][ks] = *(const bf16x8*)(smem + (CB) + brow0 + (nf << 11) + colk[ks]); } while (0)
#define RDB23(CB) do { _Pragma("unroll") for (int nf = 0; nf < 2; ++nf)        \
    _Pragma("unroll") for (int ks = 0; ks < 2; ++ks)                           \
      b23[nf][ks] = *(const bf16x8*)(smem + (CB) + brow0 + ((nf + 2) << 11) + colk[ks]); } while (0)

#define MM(BF, NB) do {                                                        \
    _Pragma("unroll") for (int mf = 0; mf < 4; ++mf)                           \
    _Pragma("unroll") for (int nf = 0; nf < 2; ++nf)                           \
    _Pragma("unroll") for (int ks = 0; ks < 2; ++ks)                           \
      acc[mf][(NB) + nf] = __builtin_amdgcn_mfma_f32_16x16x32_bf16(            \
          afr[mf][ks], BF[nf][ks], acc[mf][(NB) + nf], 0, 0, 0); } while (0)

  // ---- prologue: tile0 -> buf0, tile1 -> buf1; certify tile0; prefetch reads ----
  STG_ALL(0, 0);
  STG_ALL(1, 49152);
  asm volatile("s_waitcnt vmcnt(6)" ::: "memory");
  __builtin_amdgcn_s_barrier();
  RDA(0); RDB01(0);  // prefetch tile0 A + B01

  int bc = 0, bs = 2 * 49152;
  for (int t = 0; t < NT; ++t) {
    RDB23(bc);                 // remaining reads of tile t
    STG_ALL(t + 2, bs);        // stage tile t+2
    __builtin_amdgcn_s_setprio(1);
    MM(b01, 0);                // waits (counted) for prefetched afr/b01; b23+STG drain under it
    MM(b23, 2);
    __builtin_amdgcn_s_setprio(0);
    asm volatile("s_waitcnt vmcnt(6) lgkmcnt(0)" ::: "memory");
    __builtin_amdgcn_s_barrier();
    const int bn = (bc == 2 * 49152) ? 0 : bc + 49152;
    if (t + 1 < NT) { RDA(bn); RDB01(bn); }  // prefetch tile t+1 (certified landed)
    bc = bn;
    bs = (bs == 2 * 49152) ? 0 : bs + 49152;
  }

  // ---- epilogue: C write (D: col=lane&15, row=(lane>>4)*4+j) ----
  const int r0 = bm0 + wr * 64 + ((lane >> 4) << 2);
  const int c0 = bn0 + wc * 64 + (lane & 15);
#pragma unroll
  for (int mf = 0; mf < 4; ++mf)
#pragma unroll
    for (int nf = 0; nf < 4; ++nf) {
      const int row0 = r0 + mf * 16;
      const int col = c0 + nf * 16;
      f32x4 v = acc[mf][nf];
      const float bb = BIAS ? bias[col] : 0.0f;
      if (OUT_MODE == 0) {
        unsigned short* C = (unsigned short*)Cv + (long)blockIdx.z * sC;
#pragma unroll
        for (int j = 0; j < 4; ++j)
          C[(long)(row0 + j) * ldc + col] = f2bf(v[j] * alpha + bb);
      } else {
        float* C = (float*)Cv + (long)blockIdx.z * sC;
#pragma unroll
        for (int j = 0; j < 4; ++j)
          C[(long)(row0 + j) * ldc + col] = v[j] * alpha + bb;
      }
    }
#undef STG
#undef STG_ALL
#undef RDA
#undef RDB01
#undef RDB23
#undef MM
}

// ---------------- row softmax on bf16 scores, in place ----------------
__global__ __launch_bounds__(256) void k_softmax_bf16(unsigned short* __restrict__ S) {
  long row = blockIdx.x;
  unsigned short* R = S + row * 2048;
  int t = threadIdx.x;
  int wid = t >> 6, lane = t & 63;
  uint4 raw = reinterpret_cast<const uint4*>(R)[t];
  unsigned int w[4] = {raw.x, raw.y, raw.z, raw.w};
  float v[8];
#pragma unroll
  for (int j = 0; j < 4; ++j) {
    v[2 * j]     = __builtin_bit_cast(float, (unsigned int)(w[j] << 16));
    v[2 * j + 1] = __builtin_bit_cast(float, (unsigned int)(w[j] & 0xffff0000u));
  }
  float m = v[0];
#pragma unroll
  for (int j = 1; j < 8; ++j) m = fmaxf(m, v[j]);
#pragma unroll
  for (int off = 32; off >= 1; off >>= 1) m = fmaxf(m, __shfl_xor(m, off));
  __shared__ float red[8];
  if (lane == 0) red[wid] = m;
  __syncthreads();
  m = fmaxf(fmaxf(red[0], red[1]), fmaxf(red[2], red[3]));

  float e[8], s = 0.f;
#pragma unroll
  for (int j = 0; j < 8; ++j) { e[j] = __expf(v[j] - m); s += e[j]; }
#pragma unroll
  for (int off = 32; off >= 1; off >>= 1) s += __shfl_xor(s, off);
  if (lane == 0) red[4 + wid] = s;
  __syncthreads();
  s = red[4] + red[5] + red[6] + red[7];
  float inv = 1.0f / s;

  uint4 o;
  unsigned int* ow = &o.x;
#pragma unroll
  for (int j = 0; j < 4; ++j)
    ow[j] = (unsigned int)f2bf(e[2 * j] * inv) |
            ((unsigned int)f2bf(e[2 * j + 1] * inv) << 16);
  reinterpret_cast<uint4*>(R)[t] = o;
}

// ---------------- V [b][s][h] (stride 3072) -> Vt [b][h][s] ----------------
__global__ __launch_bounds__(256) void k_transpose_v(const unsigned short* __restrict__ V,
                                                     unsigned short* __restrict__ Vt) {
  __shared__ unsigned short tile[32][33];
  int b = blockIdx.z;
  int s0 = blockIdx.y * 32, h0 = blockIdx.x * 32;
  const unsigned short* Vb = V + (long)b * 2048 * 3072;
  unsigned short* Vtb = Vt + (long)b * 1024 * 2048;
  int tx = threadIdx.x & 31, ty = threadIdx.x >> 5;
#pragma unroll
  for (int i = 0; i < 4; ++i)
    tile[ty + 8 * i][tx] = Vb[(long)(s0 + ty + 8 * i) * 3072 + h0 + tx];
  __syncthreads();
#pragma unroll
  for (int i = 0; i < 4; ++i)
    Vtb[(long)(h0 + ty + 8 * i) * 2048 + s0 + tx] = tile[tx][ty + 8 * i];
}

extern "C" void kernel_launch(void* const* d_in, const int* in_sizes, int n_in,
                              void* d_out, int out_size, void* d_ws, size_t ws_size,
                              hipStream_t stream) {
  const float* X  = (const float*)d_in[0];
  const float* Wq = (const float*)d_in[1];
  const float* bq = (const float*)d_in[2];
  const float* Wk = (const float*)d_in[3];
  const float* bk = (const float*)d_in[4];
  const float* Wv = (const float*)d_in[5];
  const float* bv = (const float*)d_in[6];
  float* out = (float*)d_out;
  (void)in_sizes; (void)n_in; (void)out_size; (void)ws_size;

  constexpr long S = 2048, H = 1024;
  constexpr long MS = 4 * S;  // 8192 tokens

  size_t off = 0;
  auto alloc = [&](size_t bytes) { char* p = (char*)d_ws + off; off += bytes; return p; };
  unsigned short* Xb    = (unsigned short*)alloc(MS * H * 2);        // 16.8 MB
  unsigned short* Wb    = (unsigned short*)alloc(3 * H * H * 2);     // 6.3 MB (contiguous after Xb)
  float*          biasF = (float*)alloc(3 * H * 4);                  // 12 KB
  unsigned short* QKVb  = (unsigned short*)alloc(MS * 3 * H * 2);    // 50.3 MB
  unsigned short* Vt    = (unsigned short*)alloc(4 * H * S * 2);     // 16.8 MB
  unsigned short* Sb    = (unsigned short*)alloc(4 * S * S * 2);     // 33.6 MB
  (void)Wb;

  // 1) fused converts + bias
  k_prep<<<dim3(11276), 256, 0, stream>>>(X, Wq, Wk, Wv, bq, bk, bv, Xb, biasF);

  // 2) fused QKV = X @ [Wq|Wk|Wv]^T + b  (M=8192, N=3072, K=1024; bf16 out) — 768 blocks = 3.0 rounds
  gemm3p<0, 1><<<dim3(12, 64, 1), 512, 0, stream>>>(Xb, Xb + MS * H, QKVb, biasF,
                                                    1024, 1024, 3072, 1024, 1.0f, 0, 0, 0);

  // 3) scores = Q @ K^T / 32  (per batch M=2048, N=2048, K=1024; bf16 out) — 512 blocks = 2.0 rounds
  gemm3p<0, 0><<<dim3(8, 16, 4), 512, 0, stream>>>(QKVb, QKVb + 1024, Sb, nullptr,
                                                   3072, 3072, 2048, 1024, 0.03125f,
                                                   S * 3 * H, S * 3 * H, S * S);

  // 4) softmax rows in place (bf16)
  k_softmax_bf16<<<dim3((int)MS), 256, 0, stream>>>(Sb);

  // 5) V^T (from fused QKV, col offset 2048)
  k_transpose_v<<<dim3(32, 64, 4), 256, 0, stream>>>(QKVb + 2048, Vt);

  // 6) O = P @ V  (per batch M=2048, N=1024, K=2048; f32 out) — 256 blocks = 1.0 round
  gemm3p<1, 0><<<dim3(4, 16, 4), 512, 0, stream>>>(Sb, Vt, out, nullptr,
                                                   2048, 2048, 1024, 2048, 1.0f,
                                                   S * S, H * S, S * H);
}